// Round 3
// baseline (415.732 us; speedup 1.0000x reference)
//
#include <hip/hip_runtime.h>
#include <hip/hip_bf16.h>
#include <math.h>

#define DEVINL __device__ __forceinline__

// Runtime-dtype load for EXTERNAL tensors: bf=1 -> bf16, bf=0 -> f32.
DEVINL float loadIn(const void* p, long i, int bf) {
    return bf ? __bfloat162float(((const __hip_bfloat16*)p)[i])
              : ((const float*)p)[i];
}

DEVINL float leaky(float v) { return fmaxf(v, 0.2f * v); }  // branch-free

DEVINL unsigned pack_bf16(float a, float b) {
    __hip_bfloat16 x = __float2bfloat16(a), y = __float2bfloat16(b);
    unsigned short ux = *reinterpret_cast<unsigned short*>(&x);
    unsigned short uy = *reinterpret_cast<unsigned short*>(&y);
    return (unsigned)ux | ((unsigned)uy << 16);
}
DEVINL float lo16(unsigned u) { return __uint_as_float(u << 16); }
DEVINL float hi16(unsigned u) { return __uint_as_float(u & 0xFFFF0000u); }

// ---------------------------------------------------------------------------
// prep: fused dtype sniffer (proven R2-R12) + bcnt zeroing. One block.
// ---------------------------------------------------------------------------
__global__ __launch_bounds__(1024) void prep(const unsigned* __restrict__ x,
                                             int* __restrict__ flag,
                                             int* __restrict__ bcnt) {
    __shared__ int sh[1024];
    int t = threadIdx.x;
    bcnt[t] = 0;
    int cnt = 0;
    for (int i = t; i < 2048; i += 1024) {
        unsigned ex = (x[i] >> 7) & 0xFFu;
        if (ex >= 110u && ex <= 140u) cnt++;
    }
    sh[t] = cnt;
    __syncthreads();
    for (int s = 512; s > 0; s >>= 1) {
        if (t < s) sh[t] += sh[t + s];
        __syncthreads();
    }
    if (t == 0) *flag = (sh[0] >= 1200) ? 1 : 0;
}

// ---------------------------------------------------------------------------
// Two-level CSR build. Bucket = dst >> 8 (256 nodes/bucket — R12 proven).
// ---------------------------------------------------------------------------
__global__ __launch_bounds__(256) void bhist(const int* __restrict__ dst, int E,
                                             int* __restrict__ bcnt) {
    __shared__ int lh[512];
    for (int i = threadIdx.x; i < 512; i += 256) lh[i] = 0;
    __syncthreads();
    int stride = gridDim.x * 256;
    for (int e = blockIdx.x * 256 + threadIdx.x; e < E; e += stride)
        atomicAdd(&lh[dst[e] >> 8], 1);
    __syncthreads();
    for (int i = threadIdx.x; i < 512; i += 256)
        if (lh[i]) atomicAdd(&bcnt[i], lh[i]);
}

__global__ __launch_bounds__(1024) void bscan(const int* __restrict__ bcnt,
                                              int* __restrict__ bstart,
                                              int* __restrict__ bcur) {
    __shared__ int sA[1024], sB[1024];
    int t = threadIdx.x;
    int c = bcnt[t];
    sA[t] = c;
    __syncthreads();
    int* a = sA; int* b = sB;
    for (int off = 1; off < 1024; off <<= 1) {
        int v = a[t] + ((t >= off) ? a[t - off] : 0);
        __syncthreads();
        b[t] = v;
        __syncthreads();
        int* tp = a; a = b; b = tp;
    }
    int excl = a[t] - c;
    bstart[t] = excl;
    bcur[t] = excl;
    if (t == 1023) bstart[1024] = a[t];
}

// Block-aggregated reservation scatter (R13 proven).
#define CS_CHUNK 16384
__global__ __launch_bounds__(512) void block_scatter(
    const int* __restrict__ srcIdx, const int* __restrict__ dstIdx, int E,
    int* __restrict__ bcur, int* __restrict__ buf) {
    __shared__ int lh[512];
    __shared__ int lcur[512];
    int t = threadIdx.x;
    int e0 = blockIdx.x * CS_CHUNK;
    int e1 = e0 + CS_CHUNK; if (e1 > E) e1 = E;

    if (t < 512) lh[t] = 0;
    __syncthreads();
    for (int e = e0 + t; e < e1; e += 512)
        atomicAdd(&lh[dstIdx[e] >> 8], 1);
    __syncthreads();
    if (t < 512) {
        int c = lh[t];
        lcur[t] = c ? atomicAdd(&bcur[t], c) : 0;
    }
    __syncthreads();
    for (int e = e0 + t; e < e1; e += 512) {
        int d = dstIdx[e];
        int s = srcIdx[e];
        int pos = atomicAdd(&lcur[d >> 8], 1);
        buf[pos] = ((d & 255) << 17) | s;   // src < 2^17 (N=1e5)
    }
}

// fine_scatter (R12 proven): one block per 256-node bucket.
#define FS_CAP 10240
__global__ __launch_bounds__(256) void fine_scatter(
    const int* __restrict__ bstart, int* buf, int* ss,
    int* __restrict__ rp, int* __restrict__ cnt, int N) {
    __shared__ int stage[FS_CAP];
    __shared__ int hcnt[256];
    __shared__ int hA[256], hB[256];
    __shared__ int lcur[256];
    int bkt = blockIdx.x;
    int t = threadIdx.x;
    int s0 = bstart[bkt];
    int m = bstart[bkt + 1] - s0;
    if (m > FS_CAP) m = FS_CAP;

    for (int i = t; i < m; i += 256) stage[i] = buf[s0 + i];
    hcnt[t] = 0;
    __syncthreads();
    for (int i = t; i < m; i += 256) atomicAdd(&hcnt[stage[i] >> 17], 1);
    __syncthreads();
    hA[t] = hcnt[t];
    __syncthreads();
    int* a = hA; int* b = hB;
    for (int off = 1; off < 256; off <<= 1) {
        int v = a[t] + ((t >= off) ? a[t - off] : 0);
        __syncthreads();
        b[t] = v;
        __syncthreads();
        int* tp = a; a = b; b = tp;
    }
    {
        int excl = a[t] - hcnt[t];
        lcur[t] = s0 + excl;
        int node = bkt * 256 + t;
        if (node < N) {
            rp[node] = s0 + excl;
            cnt[node] = hcnt[t];
        }
    }
    __syncthreads();
    for (int i = t; i < m; i += 256) {
        int v = stage[i];
        int pos = atomicAdd(&lcur[v >> 17], 1);
        ss[pos] = v & 0x1FFFF;
    }
}

// ---------------------------------------------------------------------------
// node_transform (R15): h = x@W packed bf16x2, als/ald f32.
// HEAD-MAJOR outputs. h2: [head][N][C/2 u32] (32B rows for C=16);
// als/ald: [head][N]. Per-head arrays fit a 4MB per-XCD L2 (3.2MB + 0.4MB),
// enabling the XCD-partitioned aggregate below. H=1 layout is unchanged.
// ---------------------------------------------------------------------------
template <int XMODE, int C_IN, int H, int C>
__global__ __launch_bounds__(256) void node_transform(
    const void* __restrict__ xin, const int* __restrict__ flagp,
    const void* __restrict__ W, const void* __restrict__ a_s,
    const void* __restrict__ a_d,
    unsigned* __restrict__ h2, float* __restrict__ als,
    float* __restrict__ ald, int N)
{
    const int bf = *flagp;
    constexpr int HC = H * C;
    __shared__ float Ws[C_IN * HC];
    __shared__ float asS[HC];
    __shared__ float adS[HC];
    for (int i = threadIdx.x; i < C_IN * HC; i += 256) Ws[i] = loadIn(W, i, bf);
    for (int i = threadIdx.x; i < HC; i += 256) {
        asS[i] = loadIn(a_s, i, bf);
        adS[i] = loadIn(a_d, i, bf);
    }
    __syncthreads();

    int n = blockIdx.x * 256 + threadIdx.x;
    if (n >= N) return;

    float xv[C_IN];
    if (XMODE) {
        const uint4* x4 = (const uint4*)xin;
#pragma unroll
        for (int q = 0; q < C_IN / 8; q++) {
            uint4 w = x4[(long)n * (C_IN / 8) + q];
            xv[q * 8 + 0] = lo16(w.x); xv[q * 8 + 1] = hi16(w.x);
            xv[q * 8 + 2] = lo16(w.y); xv[q * 8 + 3] = hi16(w.y);
            xv[q * 8 + 4] = lo16(w.z); xv[q * 8 + 5] = hi16(w.z);
            xv[q * 8 + 6] = lo16(w.w); xv[q * 8 + 7] = hi16(w.w);
        }
    } else {
#pragma unroll
        for (int k = 0; k < C_IN; k++) xv[k] = loadIn(xin, (long)n * C_IN + k, bf);
    }

    float hv[HC];
#pragma unroll
    for (int j = 0; j < HC; j++) {
        float v = 0.0f;
#pragma unroll
        for (int k = 0; k < C_IN; k++) v = fmaf(xv[k], Ws[k * HC + j], v);
        hv[j] = v;
    }
    // head-major h2 store: row = C/2 u32 per (head, node)
#pragma unroll
    for (int hh = 0; hh < H; hh++)
#pragma unroll
        for (int q = 0; q < C / 2; q++)
            h2[(long)hh * N * (C / 2) + (long)n * (C / 2) + q] =
                pack_bf16(hv[hh * C + 2 * q], hv[hh * C + 2 * q + 1]);

#pragma unroll
    for (int hh = 0; hh < H; hh++) {
        float vs = 0.0f, vd = 0.0f;
#pragma unroll
        for (int c = 0; c < C; c++) {
            vs = fmaf(hv[hh * C + c], asS[hh * C + c], vs);
            vd = fmaf(hv[hh * C + c], adS[hh * C + c], vd);
        }
        als[(long)hh * N + n] = vs;
        ald[(long)hh * N + n] = vd;
    }
}

// ---------------------------------------------------------------------------
// aggregate_hs (R16 = R15 + output-index fix): head-split aggregate for
// H=2, C=16 layers. Heads are independent softmaxes, so each (node, head)
// is an independent work item. Head is chosen by blockIdx%8 (XCD
// round-robin): XCDs 0-3 -> head 0, XCDs 4-7 -> head 1. Each XCD then only
// gathers ITS head's h2 (3.2MB) + als (0.4MB), which fits the 4MB per-XCD
// L2 -> kills the ~2.1x h2 refetch thrash (R14 FETCH 127MB vs ~51MB
// compulsory). Also halves gather-instr count (64-lane gather covers 16
// edges instead of 8).
// Output row is 16 u32 (= 8 uint2): node stride 8, head offset 4 (R16 fix;
// R15 had node*4 + head*2 -> overlapping heads).
// ---------------------------------------------------------------------------
template <int UNR>
__global__ __launch_bounds__(256) void aggregate_hs(
    const int* __restrict__ rp_start, const int* __restrict__ cnt,
    const int* __restrict__ ss,
    const unsigned* __restrict__ h2,      // head-major: [head][N][8 u32]
    const float* __restrict__ als, const float* __restrict__ ald, // [head][N]
    const void* __restrict__ bias, const int* __restrict__ flagp,
    unsigned* __restrict__ xout, int N)   // node-major: [N][16 u32]
{
    constexpr int C = 16, NCH = 4, J = C / NCH;   // J=4
    constexpr int EPW = 64 / J;                    // 16 edge rows per wave
    const int bf = *flagp;
    int lane = threadIdx.x & 63;
    int p = lane >> 2;          // edge-row group 0..15
    int j = lane & 3;           // channel quad 0..3
    int c0 = NCH * j;

    int head = (blockIdx.x >> 2) & 1;                       // bid%8<4 -> 0
    int r = ((blockIdx.x >> 3) << 2) | (blockIdx.x & 3);    // rank in head
    const unsigned* __restrict__ h2h = h2 + (long)head * N * 8;
    const float* __restrict__ alsh = als + (long)head * N;
    const float* __restrict__ aldh = ald + (long)head * N;

    float bv[NCH];
#pragma unroll
    for (int i = 0; i < NCH; i++) bv[i] = loadIn(bias, head * C + c0 + i, bf);

    const int nstride = gridDim.x << 1;   // (gridDim/2 blocks per head) * 4 waves
    for (int node = (r << 2) + (threadIdx.x >> 6); node < N; node += nstride) {

        int start = rp_start[node];
        int deg = cnt[node];
        int degm1 = deg - 1;
        float ald_n = aldh[node];

        float acc[NCH];
        float ssum = 0.0f;
#pragma unroll
        for (int i = 0; i < NCH; i++) acc[i] = 0.0f;

        // ---- self-loop on p==0 lanes (j=0..3 cover the 4 uint2 of the row)
        if (p == 0) {
            float es = __expf(fminf(leaky(alsh[node] + ald_n), 80.0f));
            uint2 hv = ((const uint2*)h2h)[node * 4 + j];
            acc[0] = lo16(hv.x) * es; acc[1] = hi16(hv.x) * es;
            acc[2] = lo16(hv.y) * es; acc[3] = hi16(hv.y) * es;
            ssum = es;
        }

        // ---- UNR-unrolled single pass over edges (batched gathers)
        for (int kb = p; kb < deg; kb += UNR * EPW) {
            int srcs[UNR];
            bool ok[UNR];
#pragma unroll
            for (int u = 0; u < UNR; u++) {
                int k = kb + u * EPW;
                ok[u] = (k < deg);
                int kc = ok[u] ? k : degm1;
                srcs[u] = ss[start + kc];
            }
            float av[UNR];
            uint2 hv4[UNR];
#pragma unroll
            for (int u = 0; u < UNR; u++) {
                av[u] = alsh[srcs[u]];
                hv4[u] = ((const uint2*)h2h)[srcs[u] * 4 + j];
            }
#pragma unroll
            for (int u = 0; u < UNR; u++) {
                float e = ok[u] ? __expf(fminf(leaky(av[u] + ald_n), 80.0f)) : 0.0f;
                acc[0] = fmaf(lo16(hv4[u].x), e, acc[0]);
                acc[1] = fmaf(hi16(hv4[u].x), e, acc[1]);
                acc[2] = fmaf(lo16(hv4[u].y), e, acc[2]);
                acc[3] = fmaf(hi16(hv4[u].y), e, acc[3]);
                ssum += e;
            }
        }

        // ---- plain-add butterfly across the 16 p groups
#pragma unroll
        for (int off = J; off < 64; off <<= 1) {
#pragma unroll
            for (int i = 0; i < NCH; i++) acc[i] += __shfl_xor(acc[i], off, 64);
            ssum += __shfl_xor(ssum, off, 64);
        }

        float inv = 1.0f / (ssum + 1e-16f);   // precise div kept (numerics)
        float v[NCH];
#pragma unroll
        for (int i = 0; i < NCH; i++) {
            float t = acc[i] * inv + bv[i];
            float en = __expf(fminf(t, 0.0f)) - 1.0f;  // ELU, native exp
            v[i] = t > 0.0f ? t : en;
        }

        if (p == 0) {
            // node-major output row = 16 u32 = 8 uint2. Channel c -> u32 c/2;
            // head h covers u32 [8h, 8h+8) = uint2 [4h, 4h+4). (R16 fix)
            uint2 o; o.x = pack_bf16(v[0], v[1]); o.y = pack_bf16(v[2], v[3]);
            ((uint2*)xout)[node * 8 + head * 4 + j] = o;
        }
    }
}

// ---------------------------------------------------------------------------
// aggregate (R14 structure) — now only instantiated for layer 3 (H=1,C=8),
// whose h2 (1.6MB) already fits per-XCD L2. Head-major layout with H=1 is
// identical to the old layout, so indexing is unchanged.
// ---------------------------------------------------------------------------
template <int H, int C, int NCH, int UNR, int FUSE>
__global__ __launch_bounds__(256) void aggregate(
    const int* __restrict__ rp_start, const int* __restrict__ cnt,
    const int* __restrict__ ss,
    const unsigned* __restrict__ h2,
    const float* __restrict__ als, const float* __restrict__ ald,
    const void* __restrict__ bias, const void* __restrict__ Wo,
    const void* __restrict__ bo, const int* __restrict__ flagp,
    void* __restrict__ xout, int N)
{
    constexpr int HC = H * C;
    constexpr int J = HC / NCH;     // lanes per edge row
    constexpr int EPW = 64 / J;     // edge rows per wave
    const int bf = *flagp;
    int lane = threadIdx.x & 63;
    int p = lane / J;
    int j = lane % J;
    int c0 = NCH * j;
    int head = c0 / C;
    const float* __restrict__ alsH = als + head;

    float bv[NCH];
#pragma unroll
    for (int i = 0; i < NCH; i++) bv[i] = loadIn(bias, c0 + i, bf);
    float wov[NCH];
    float bov = 0.0f;
    if constexpr (FUSE) {
#pragma unroll
        for (int i = 0; i < NCH; i++) wov[i] = loadIn(Wo, c0 + i, bf);
        bov = loadIn(bo, 0, bf);
    }

    const int nstride = gridDim.x << 2;   // 4 waves per block
    for (int node = (blockIdx.x << 2) + (threadIdx.x >> 6); node < N;
         node += nstride) {

        int start = rp_start[node];
        int deg = cnt[node];
        int degm1 = deg - 1;
        float ald_n = ald[node * H + head];

        float acc[NCH];
        float ssum = 0.0f;
#pragma unroll
        for (int i = 0; i < NCH; i++) acc[i] = 0.0f;

        if (p == 0) {
            float es = __expf(fminf(leaky(alsH[node * H] + ald_n), 80.0f));
            if constexpr (NCH == 4) {
                uint2 hv = ((const uint2*)h2)[node * (HC / 4) + j];
                acc[0] = lo16(hv.x) * es; acc[1] = hi16(hv.x) * es;
                acc[2] = lo16(hv.y) * es; acc[3] = hi16(hv.y) * es;
            } else {
                unsigned hv = h2[node * (HC / 2) + j];
                acc[0] = lo16(hv) * es; acc[1] = hi16(hv) * es;
            }
            ssum = es;
        }

        for (int kb = p; kb < deg; kb += UNR * EPW) {
            int srcs[UNR];
            bool ok[UNR];
#pragma unroll
            for (int u = 0; u < UNR; u++) {
                int k = kb + u * EPW;
                ok[u] = (k < deg);
                int kc = ok[u] ? k : degm1;
                srcs[u] = ss[start + kc];
            }
            float av[UNR];
            uint2 hv4[UNR];
            unsigned hv2[UNR];
#pragma unroll
            for (int u = 0; u < UNR; u++) {
                av[u] = alsH[srcs[u] * H];
                if constexpr (NCH == 4)
                    hv4[u] = ((const uint2*)h2)[srcs[u] * (HC / 4) + j];
                else
                    hv2[u] = h2[srcs[u] * (HC / 2) + j];
            }
#pragma unroll
            for (int u = 0; u < UNR; u++) {
                float e = ok[u] ? __expf(fminf(leaky(av[u] + ald_n), 80.0f)) : 0.0f;
                if constexpr (NCH == 4) {
                    acc[0] = fmaf(lo16(hv4[u].x), e, acc[0]);
                    acc[1] = fmaf(hi16(hv4[u].x), e, acc[1]);
                    acc[2] = fmaf(lo16(hv4[u].y), e, acc[2]);
                    acc[3] = fmaf(hi16(hv4[u].y), e, acc[3]);
                } else {
                    acc[0] = fmaf(lo16(hv2[u]), e, acc[0]);
                    acc[1] = fmaf(hi16(hv2[u]), e, acc[1]);
                }
                ssum += e;
            }
        }

#pragma unroll
        for (int off = J; off < 64; off <<= 1) {
#pragma unroll
            for (int i = 0; i < NCH; i++) acc[i] += __shfl_xor(acc[i], off, 64);
            ssum += __shfl_xor(ssum, off, 64);
        }

        float inv = 1.0f / (ssum + 1e-16f);
        float v[NCH];
#pragma unroll
        for (int i = 0; i < NCH; i++) {
            float t = acc[i] * inv + bv[i];
            float en = __expf(fminf(t, 0.0f)) - 1.0f;  // ELU, native exp
            v[i] = t > 0.0f ? t : en;
        }

        if (FUSE) {
            float r = 0.0f;
#pragma unroll
            for (int i = 0; i < NCH; i++) r = fmaf(v[i], wov[i], r);
#pragma unroll
            for (int off = 1; off < J; off <<= 1) r += __shfl_xor(r, off, 64);
            if (lane == 0) {
                r += bov;
                if (bf) ((__hip_bfloat16*)xout)[node] = __float2bfloat16(r);
                else    ((float*)xout)[node] = r;
            }
        } else {
            if (p == 0) {
                if constexpr (NCH == 4) {
                    uint2 o; o.x = pack_bf16(v[0], v[1]); o.y = pack_bf16(v[2], v[3]);
                    ((uint2*)xout)[node * (HC / 4) + j] = o;
                } else {
                    ((unsigned*)xout)[node * (HC / 2) + j] = pack_bf16(v[0], v[1]);
                }
            }
        }
    }
}

// ---------------------------------------------------------------------------
extern "C" void kernel_launch(void* const* d_in, const int* in_sizes, int n_in,
                              void* d_out, int out_size, void* d_ws, size_t ws_size,
                              hipStream_t stream) {
    const void* x   = d_in[0];
    const int*  ei  = (const int*)d_in[1];
    const void* W1  = d_in[2];
    const void* as1 = d_in[3];
    const void* ad1 = d_in[4];
    const void* b1  = d_in[5];
    const void* W2  = d_in[6];
    const void* as2 = d_in[7];
    const void* ad2 = d_in[8];
    const void* b2  = d_in[9];
    const void* W3  = d_in[10];
    const void* as3 = d_in[11];
    const void* ad3 = d_in[12];
    const void* b3  = d_in[13];
    const void* Wo  = d_in[14];
    const void* bo  = d_in[15];

    const int N = in_sizes[0] / 3;
    const int E = in_sizes[1] / 2;
    const int* ei0 = ei;       // src
    const int* ei1 = ei + E;   // dst

    // ---- ws layout (~28.0 MB @ N=1e5, E=3.2e6; fits proven <32MB budget)
    int* flag   = (int*)d_ws;              // 64
    int* bcnt   = flag + 64;               // 1024
    int* bstart = bcnt + 1024;             // 1025 (padded 1088)
    int* bcur   = bstart + 1088;           // 1024
    int* cnt    = bcur + 1024;             // N
    int* rp     = cnt + N;                 // N
    int* ss     = rp + N;                  // E  (phase-A buf aliases this)
    float* als  = (float*)(ss + E);        // N*2 (head-major [2][N])
    float* ald  = als + (long)N * 2;       // N*2 (head-major [2][N])
    unsigned* A = (unsigned*)(ald + (long)N * 2); // N*16 u32
    unsigned* h = A + (long)N * 16;               // N*16 u32 ([2][N][8] u32)

    const int B = 256;
    auto cdiv = [](long a, long b) { return (int)((a + b - 1) / b); };
    const int NBKT = cdiv(N, 256);   // 256-node buckets (R12)

    // persistent grids: 2048 blocks x 4 waves = 8 blocks/CU = 32 waves/CU.
    // aggregate_hs needs grid % 8 == 0 (head = XCD via blockIdx%8).
    const int aggBlocks = 2048;

    // ---- two-level CSR build (dst-sorted), once, reused by all 3 layers
    prep<<<1, 1024, 0, stream>>>((const unsigned*)x, flag, bcnt);
    bhist<<<256, B, 0, stream>>>(ei1, E, bcnt);
    bscan<<<1, 1024, 0, stream>>>(bcnt, bstart, bcur);
    block_scatter<<<cdiv(E, CS_CHUNK), 512, 0, stream>>>(ei0, ei1, E, bcur, ss);
    fine_scatter<<<NBKT, B, 0, stream>>>(bstart, ss, ss, rp, cnt, N);

    // ---- Layer 1: 3 -> 2x16 (head-split aggregate, XCD-partitioned)
    node_transform<0, 3, 2, 16><<<cdiv(N, B), B, 0, stream>>>(
        x, flag, W1, as1, ad1, h, als, ald, N);
    aggregate_hs<3><<<aggBlocks, B, 0, stream>>>(
        rp, cnt, ss, h, als, ald, b1, flag, A, N);

    // ---- Layer 2: 32 -> 2x16 (head-split aggregate, XCD-partitioned)
    node_transform<1, 32, 2, 16><<<cdiv(N, B), B, 0, stream>>>(
        A, flag, W2, as2, ad2, h, als, ald, N);
    aggregate_hs<3><<<aggBlocks, B, 0, stream>>>(
        rp, cnt, ss, h, als, ald, b2, flag, A, N);

    // ---- Layer 3: 32 -> 1x8, fused output head (h2 1.6MB already L2-fit)
    node_transform<1, 32, 1, 8><<<cdiv(N, B), B, 0, stream>>>(
        A, flag, W3, as3, ad3, h, als, ald, N);
    aggregate<1, 8, 2, 3, 1><<<aggBlocks, B, 0, stream>>>(
        rp, cnt, ss, h, als, ald, b3, Wo, bo, flag, d_out, N);
}

// Round 4
// 323.204 us; speedup vs baseline: 1.2863x; 1.2863x over previous
//
#include <hip/hip_runtime.h>
#include <hip/hip_bf16.h>
#include <math.h>

#define DEVINL __device__ __forceinline__

// Runtime-dtype load for EXTERNAL tensors: bf=1 -> bf16, bf=0 -> f32.
DEVINL float loadIn(const void* p, long i, int bf) {
    return bf ? __bfloat162float(((const __hip_bfloat16*)p)[i])
              : ((const float*)p)[i];
}

DEVINL float leaky(float v) { return fmaxf(v, 0.2f * v); }  // branch-free

DEVINL unsigned pack_bf16(float a, float b) {
    __hip_bfloat16 x = __float2bfloat16(a), y = __float2bfloat16(b);
    unsigned short ux = *reinterpret_cast<unsigned short*>(&x);
    unsigned short uy = *reinterpret_cast<unsigned short*>(&y);
    return (unsigned)ux | ((unsigned)uy << 16);
}
DEVINL float lo16(unsigned u) { return __uint_as_float(u << 16); }
DEVINL float hi16(unsigned u) { return __uint_as_float(u & 0xFFFF0000u); }

// ---------------------------------------------------------------------------
// prep: fused dtype sniffer (proven R2-R12) + bcnt zeroing. One block.
// ---------------------------------------------------------------------------
__global__ __launch_bounds__(1024) void prep(const unsigned* __restrict__ x,
                                             int* __restrict__ flag,
                                             int* __restrict__ bcnt) {
    __shared__ int sh[1024];
    int t = threadIdx.x;
    bcnt[t] = 0;
    int cnt = 0;
    for (int i = t; i < 2048; i += 1024) {
        unsigned ex = (x[i] >> 7) & 0xFFu;
        if (ex >= 110u && ex <= 140u) cnt++;
    }
    sh[t] = cnt;
    __syncthreads();
    for (int s = 512; s > 0; s >>= 1) {
        if (t < s) sh[t] += sh[t + s];
        __syncthreads();
    }
    if (t == 0) *flag = (sh[0] >= 1200) ? 1 : 0;
}

// ---------------------------------------------------------------------------
// Two-level CSR build. Bucket = dst >> 8 (256 nodes/bucket — R12 proven).
// ---------------------------------------------------------------------------
__global__ __launch_bounds__(256) void bhist(const int* __restrict__ dst, int E,
                                             int* __restrict__ bcnt) {
    __shared__ int lh[512];
    for (int i = threadIdx.x; i < 512; i += 256) lh[i] = 0;
    __syncthreads();
    int stride = gridDim.x * 256;
    for (int e = blockIdx.x * 256 + threadIdx.x; e < E; e += stride)
        atomicAdd(&lh[dst[e] >> 8], 1);
    __syncthreads();
    for (int i = threadIdx.x; i < 512; i += 256)
        if (lh[i]) atomicAdd(&bcnt[i], lh[i]);
}

__global__ __launch_bounds__(1024) void bscan(const int* __restrict__ bcnt,
                                              int* __restrict__ bstart,
                                              int* __restrict__ bcur) {
    __shared__ int sA[1024], sB[1024];
    int t = threadIdx.x;
    int c = bcnt[t];
    sA[t] = c;
    __syncthreads();
    int* a = sA; int* b = sB;
    for (int off = 1; off < 1024; off <<= 1) {
        int v = a[t] + ((t >= off) ? a[t - off] : 0);
        __syncthreads();
        b[t] = v;
        __syncthreads();
        int* tp = a; a = b; b = tp;
    }
    int excl = a[t] - c;
    bstart[t] = excl;
    bcur[t] = excl;
    if (t == 1023) bstart[1024] = a[t];
}

// Block-aggregated reservation scatter (R13 proven).
#define CS_CHUNK 16384
__global__ __launch_bounds__(512) void block_scatter(
    const int* __restrict__ srcIdx, const int* __restrict__ dstIdx, int E,
    int* __restrict__ bcur, int* __restrict__ buf) {
    __shared__ int lh[512];
    __shared__ int lcur[512];
    int t = threadIdx.x;
    int e0 = blockIdx.x * CS_CHUNK;
    int e1 = e0 + CS_CHUNK; if (e1 > E) e1 = E;

    if (t < 512) lh[t] = 0;
    __syncthreads();
    for (int e = e0 + t; e < e1; e += 512)
        atomicAdd(&lh[dstIdx[e] >> 8], 1);
    __syncthreads();
    if (t < 512) {
        int c = lh[t];
        lcur[t] = c ? atomicAdd(&bcur[t], c) : 0;
    }
    __syncthreads();
    for (int e = e0 + t; e < e1; e += 512) {
        int d = dstIdx[e];
        int s = srcIdx[e];
        int pos = atomicAdd(&lcur[d >> 8], 1);
        buf[pos] = ((d & 255) << 17) | s;   // src < 2^17 (N=1e5)
    }
}

// fine_scatter (R12 proven): one block per 256-node bucket.
#define FS_CAP 10240
__global__ __launch_bounds__(256) void fine_scatter(
    const int* __restrict__ bstart, int* buf, int* ss,
    int* __restrict__ rp, int* __restrict__ cnt, int N) {
    __shared__ int stage[FS_CAP];
    __shared__ int hcnt[256];
    __shared__ int hA[256], hB[256];
    __shared__ int lcur[256];
    int bkt = blockIdx.x;
    int t = threadIdx.x;
    int s0 = bstart[bkt];
    int m = bstart[bkt + 1] - s0;
    if (m > FS_CAP) m = FS_CAP;

    for (int i = t; i < m; i += 256) stage[i] = buf[s0 + i];
    hcnt[t] = 0;
    __syncthreads();
    for (int i = t; i < m; i += 256) atomicAdd(&hcnt[stage[i] >> 17], 1);
    __syncthreads();
    hA[t] = hcnt[t];
    __syncthreads();
    int* a = hA; int* b = hB;
    for (int off = 1; off < 256; off <<= 1) {
        int v = a[t] + ((t >= off) ? a[t - off] : 0);
        __syncthreads();
        b[t] = v;
        __syncthreads();
        int* tp = a; a = b; b = tp;
    }
    {
        int excl = a[t] - hcnt[t];
        lcur[t] = s0 + excl;
        int node = bkt * 256 + t;
        if (node < N) {
            rp[node] = s0 + excl;
            cnt[node] = hcnt[t];
        }
    }
    __syncthreads();
    for (int i = t; i < m; i += 256) {
        int v = stage[i];
        int pos = atomicAdd(&lcur[v >> 17], 1);
        ss[pos] = v & 0x1FFFF;
    }
}

// ---------------------------------------------------------------------------
// xprep (R17): pad x -> xp[N][4] f32 (16B rows, single-uint4 gather target
// for aggregate_l1). Block 0 also computes the commuted attention vectors:
//   cs[h][k] = sum_c W1[k][16h+c]*as1[h][c]   (als_1 = x . cs_h)
//   cd[h][k] = sum_c W1[k][16h+c]*ad1[h][c]   (ald_1 = x . cd_h)
// cvec[0..5] = cs, cvec[6..11] = cd.
// ---------------------------------------------------------------------------
__global__ __launch_bounds__(256) void xprep(
    const void* __restrict__ x, const int* __restrict__ flagp,
    const void* __restrict__ W1, const void* __restrict__ as1,
    const void* __restrict__ ad1,
    float4* __restrict__ xp, float* __restrict__ cvec, int N)
{
    const int bf = *flagp;
    int n = blockIdx.x * 256 + threadIdx.x;
    if (n < N) {
        float4 v;
        v.x = loadIn(x, (long)n * 3 + 0, bf);
        v.y = loadIn(x, (long)n * 3 + 1, bf);
        v.z = loadIn(x, (long)n * 3 + 2, bf);
        v.w = 0.0f;
        xp[n] = v;
    }
    if (blockIdx.x == 0 && threadIdx.x < 12) {
        int t = threadIdx.x;
        int isd = t >= 6;
        int h = (t - 6 * isd) / 3;
        int k = (t - 6 * isd) % 3;
        const void* av = isd ? ad1 : as1;
        float s = 0.0f;
        for (int c = 0; c < 16; c++)
            s += loadIn(W1, k * 32 + h * 16 + c, bf) * loadIn(av, h * 16 + c, bf);
        cvec[t] = s;
    }
}

// ---------------------------------------------------------------------------
// aggregate_l1 (R17): layer-1 GAT via the commuted form
//   out_h = ELU( (sum_e alpha_e * x_src) @ W1[:,16h:16h+16] + b1 ),
//   logits from als = x.cs_h, ald = x.cd_h (cvec, precomputed).
// Gathers ONLY xp[src] (16B, one line, one instr per edge) -- working set
// 1.6MB, L2-resident for BOTH heads. One lane per edge (no 8x redundant
// exp), 16 lanes per node, 4 nodes per wave, UNR=2 for MLP.
// R3 post-mortem: head-split doubled fixed costs for no latency win; this
// shrinks the payload instead of partitioning it.
// ---------------------------------------------------------------------------
__global__ __launch_bounds__(256) void aggregate_l1(
    const int* __restrict__ rp_start, const int* __restrict__ cnt,
    const int* __restrict__ ss, const float4* __restrict__ xp,
    const float* __restrict__ cvec,
    const void* __restrict__ W1, const void* __restrict__ b1,
    const int* __restrict__ flagp,
    unsigned* __restrict__ xout, int N)   // xout: node-major [N][16 u32]
{
    const int bf = *flagp;
    __shared__ float Wl[96];   // W1 3x32 f32
    __shared__ float bl[32];
    for (int i = threadIdx.x; i < 96; i += 256) Wl[i] = loadIn(W1, i, bf);
    for (int i = threadIdx.x; i < 32; i += 256) bl[i] = loadIn(b1, i, bf);
    __syncthreads();

    int lane = threadIdx.x & 63;
    int g = lane >> 4;          // node sub-index within wave (0..3)
    int q = lane & 15;          // edge slot / output-channel-pair index
    int wid = threadIdx.x >> 6; // wave in block (0..3)

    float cs[2][3], cd[2][3];
#pragma unroll
    for (int h = 0; h < 2; h++)
#pragma unroll
        for (int k = 0; k < 3; k++) {
            cs[h][k] = cvec[h * 3 + k];
            cd[h][k] = cvec[6 + h * 3 + k];
        }

    const int nstride = gridDim.x * 16;   // 4 waves * 4 nodes per block
    for (int node = blockIdx.x * 16 + wid * 4 + g; ; node += nstride) {
        // wave exits together: all 4 sub-nodes past N
        if (node - g >= N) break;   // node-g = wave base+... conservative per-lane
        bool valid = node < N;
        int idx = valid ? node : 0;
        int start = rp_start[idx];
        int deg = valid ? cnt[idx] : 0;
        float4 xn = xp[idx];

        float alsn[2], aldn[2];
#pragma unroll
        for (int h = 0; h < 2; h++) {
            alsn[h] = xn.x * cs[h][0] + xn.y * cs[h][1] + xn.z * cs[h][2];
            aldn[h] = xn.x * cd[h][0] + xn.y * cd[h][1] + xn.z * cd[h][2];
        }

        float a00 = 0.f, a01 = 0.f, a02 = 0.f, s0 = 0.f;
        float a10 = 0.f, a11 = 0.f, a12 = 0.f, s1 = 0.f;

        // self-loop on slot 0
        if (q == 0 && valid) {
            float e0 = __expf(fminf(leaky(alsn[0] + aldn[0]), 80.0f));
            float e1 = __expf(fminf(leaky(alsn[1] + aldn[1]), 80.0f));
            a00 = e0 * xn.x; a01 = e0 * xn.y; a02 = e0 * xn.z; s0 = e0;
            a10 = e1 * xn.x; a11 = e1 * xn.y; a12 = e1 * xn.z; s1 = e1;
        }

        // one edge per lane, UNR=2 (2 gathers in flight)
        for (int kb = q; kb < deg; kb += 32) {
            int k2 = kb + 16;
            bool ok2 = k2 < deg;
            int sA = ss[start + kb];
            int sB = ss[start + (ok2 ? k2 : kb)];
            float4 xa = xp[sA];
            float4 xb = xp[sB];
            {
                float l0 = xa.x * cs[0][0] + xa.y * cs[0][1] + xa.z * cs[0][2] + aldn[0];
                float l1 = xa.x * cs[1][0] + xa.y * cs[1][1] + xa.z * cs[1][2] + aldn[1];
                float e0 = __expf(fminf(leaky(l0), 80.0f));
                float e1 = __expf(fminf(leaky(l1), 80.0f));
                a00 = fmaf(xa.x, e0, a00); a01 = fmaf(xa.y, e0, a01);
                a02 = fmaf(xa.z, e0, a02); s0 += e0;
                a10 = fmaf(xa.x, e1, a10); a11 = fmaf(xa.y, e1, a11);
                a12 = fmaf(xa.z, e1, a12); s1 += e1;
            }
            {
                float l0 = xb.x * cs[0][0] + xb.y * cs[0][1] + xb.z * cs[0][2] + aldn[0];
                float l1 = xb.x * cs[1][0] + xb.y * cs[1][1] + xb.z * cs[1][2] + aldn[1];
                float e0 = ok2 ? __expf(fminf(leaky(l0), 80.0f)) : 0.0f;
                float e1 = ok2 ? __expf(fminf(leaky(l1), 80.0f)) : 0.0f;
                a00 = fmaf(xb.x, e0, a00); a01 = fmaf(xb.y, e0, a01);
                a02 = fmaf(xb.z, e0, a02); s0 += e0;
                a10 = fmaf(xb.x, e1, a10); a11 = fmaf(xb.y, e1, a11);
                a12 = fmaf(xb.z, e1, a12); s1 += e1;
            }
        }

        // butterfly within the 16-lane group (off = 1,2,4,8)
#pragma unroll
        for (int off = 1; off < 16; off <<= 1) {
            a00 += __shfl_xor(a00, off, 64); a01 += __shfl_xor(a01, off, 64);
            a02 += __shfl_xor(a02, off, 64); s0  += __shfl_xor(s0,  off, 64);
            a10 += __shfl_xor(a10, off, 64); a11 += __shfl_xor(a11, off, 64);
            a12 += __shfl_xor(a12, off, 64); s1  += __shfl_xor(s1,  off, 64);
        }

        // epilogue: lane q -> channels 2q, 2q+1 (head = q>>3)
        if (valid) {
            int h = q >> 3;
            float inv = 1.0f / ((h ? s1 : s0) + 1e-16f);
            float g0 = (h ? a10 : a00) * inv;
            float g1 = (h ? a11 : a01) * inv;
            float g2 = (h ? a12 : a02) * inv;
            int c0 = 2 * q;
            float v0 = g0 * Wl[c0]      + g1 * Wl[32 + c0]      + g2 * Wl[64 + c0]      + bl[c0];
            float v1 = g0 * Wl[c0 + 1]  + g1 * Wl[32 + c0 + 1]  + g2 * Wl[64 + c0 + 1]  + bl[c0 + 1];
            v0 = v0 > 0.0f ? v0 : __expf(fminf(v0, 0.0f)) - 1.0f;   // ELU
            v1 = v1 > 0.0f ? v1 : __expf(fminf(v1, 0.0f)) - 1.0f;
            xout[(long)node * 16 + q] = pack_bf16(v0, v1);
        }
    }
}

// ---------------------------------------------------------------------------
// node_transform (R9/R1 proven, node-major): h = x@W (packed bf16x2),
// als/ald f32 node-major [N][H]. Used for layers 2-3 only.
// ---------------------------------------------------------------------------
template <int XMODE, int C_IN, int H, int C>
__global__ __launch_bounds__(256) void node_transform(
    const void* __restrict__ xin, const int* __restrict__ flagp,
    const void* __restrict__ W, const void* __restrict__ a_s,
    const void* __restrict__ a_d,
    unsigned* __restrict__ h2, float* __restrict__ als,
    float* __restrict__ ald, int N)
{
    const int bf = *flagp;
    constexpr int HC = H * C;
    __shared__ float Ws[C_IN * HC];
    __shared__ float asS[HC];
    __shared__ float adS[HC];
    for (int i = threadIdx.x; i < C_IN * HC; i += 256) Ws[i] = loadIn(W, i, bf);
    for (int i = threadIdx.x; i < HC; i += 256) {
        asS[i] = loadIn(a_s, i, bf);
        adS[i] = loadIn(a_d, i, bf);
    }
    __syncthreads();

    int n = blockIdx.x * 256 + threadIdx.x;
    if (n >= N) return;

    float xv[C_IN];
    if (XMODE) {
        const uint4* x4 = (const uint4*)xin;
#pragma unroll
        for (int q = 0; q < C_IN / 8; q++) {
            uint4 w = x4[(long)n * (C_IN / 8) + q];
            xv[q * 8 + 0] = lo16(w.x); xv[q * 8 + 1] = hi16(w.x);
            xv[q * 8 + 2] = lo16(w.y); xv[q * 8 + 3] = hi16(w.y);
            xv[q * 8 + 4] = lo16(w.z); xv[q * 8 + 5] = hi16(w.z);
            xv[q * 8 + 6] = lo16(w.w); xv[q * 8 + 7] = hi16(w.w);
        }
    } else {
#pragma unroll
        for (int k = 0; k < C_IN; k++) xv[k] = loadIn(xin, (long)n * C_IN + k, bf);
    }

    float hv[HC];
#pragma unroll
    for (int j = 0; j < HC; j++) {
        float v = 0.0f;
#pragma unroll
        for (int k = 0; k < C_IN; k++) v = fmaf(xv[k], Ws[k * HC + j], v);
        hv[j] = v;
    }
#pragma unroll
    for (int jj = 0; jj < HC / 2; jj++)
        h2[(long)n * (HC / 2) + jj] = pack_bf16(hv[2 * jj], hv[2 * jj + 1]);

#pragma unroll
    for (int hh = 0; hh < H; hh++) {
        float vs = 0.0f, vd = 0.0f;
#pragma unroll
        for (int c = 0; c < C; c++) {
            vs = fmaf(hv[hh * C + c], asS[hh * C + c], vs);
            vd = fmaf(hv[hh * C + c], adS[hh * C + c], vd);
        }
        als[(long)n * H + hh] = vs;
        ald[(long)n * H + hh] = vd;
    }
}

// ---------------------------------------------------------------------------
// aggregate (R14 proven, 70us @ HC=32): combined-heads, node-major layout.
// Used for layers 2-3. R3 proved head-split regresses (2x fixed costs);
// this stays combined.
// ---------------------------------------------------------------------------
template <int H, int C, int NCH, int UNR, int FUSE>
__global__ __launch_bounds__(256) void aggregate(
    const int* __restrict__ rp_start, const int* __restrict__ cnt,
    const int* __restrict__ ss,
    const unsigned* __restrict__ h2,
    const float* __restrict__ als, const float* __restrict__ ald,
    const void* __restrict__ bias, const void* __restrict__ Wo,
    const void* __restrict__ bo, const int* __restrict__ flagp,
    void* __restrict__ xout, int N)
{
    constexpr int HC = H * C;
    constexpr int J = HC / NCH;     // lanes per edge row
    constexpr int EPW = 64 / J;     // edge rows per wave
    const int bf = *flagp;
    int lane = threadIdx.x & 63;
    int p = lane / J;
    int j = lane % J;
    int c0 = NCH * j;
    int head = c0 / C;
    const float* __restrict__ alsH = als + head;

    float bv[NCH];
#pragma unroll
    for (int i = 0; i < NCH; i++) bv[i] = loadIn(bias, c0 + i, bf);
    float wov[NCH];
    float bov = 0.0f;
    if constexpr (FUSE) {
#pragma unroll
        for (int i = 0; i < NCH; i++) wov[i] = loadIn(Wo, c0 + i, bf);
        bov = loadIn(bo, 0, bf);
    }

    const int nstride = gridDim.x << 2;   // 4 waves per block
    for (int node = (blockIdx.x << 2) + (threadIdx.x >> 6); node < N;
         node += nstride) {

        int start = rp_start[node];
        int deg = cnt[node];
        int degm1 = deg - 1;
        float ald_n = ald[node * H + head];

        float acc[NCH];
        float ssum = 0.0f;
#pragma unroll
        for (int i = 0; i < NCH; i++) acc[i] = 0.0f;

        if (p == 0) {
            float es = __expf(fminf(leaky(alsH[node * H] + ald_n), 80.0f));
            if constexpr (NCH == 4) {
                uint2 hv = ((const uint2*)h2)[node * (HC / 4) + j];
                acc[0] = lo16(hv.x) * es; acc[1] = hi16(hv.x) * es;
                acc[2] = lo16(hv.y) * es; acc[3] = hi16(hv.y) * es;
            } else {
                unsigned hv = h2[node * (HC / 2) + j];
                acc[0] = lo16(hv) * es; acc[1] = hi16(hv) * es;
            }
            ssum = es;
        }

        for (int kb = p; kb < deg; kb += UNR * EPW) {
            int srcs[UNR];
            bool ok[UNR];
#pragma unroll
            for (int u = 0; u < UNR; u++) {
                int k = kb + u * EPW;
                ok[u] = (k < deg);
                int kc = ok[u] ? k : degm1;
                srcs[u] = ss[start + kc];
            }
            float av[UNR];
            uint2 hv4[UNR];
            unsigned hv2[UNR];
#pragma unroll
            for (int u = 0; u < UNR; u++) {
                av[u] = alsH[srcs[u] * H];
                if constexpr (NCH == 4)
                    hv4[u] = ((const uint2*)h2)[srcs[u] * (HC / 4) + j];
                else
                    hv2[u] = h2[srcs[u] * (HC / 2) + j];
            }
#pragma unroll
            for (int u = 0; u < UNR; u++) {
                float e = ok[u] ? __expf(fminf(leaky(av[u] + ald_n), 80.0f)) : 0.0f;
                if constexpr (NCH == 4) {
                    acc[0] = fmaf(lo16(hv4[u].x), e, acc[0]);
                    acc[1] = fmaf(hi16(hv4[u].x), e, acc[1]);
                    acc[2] = fmaf(lo16(hv4[u].y), e, acc[2]);
                    acc[3] = fmaf(hi16(hv4[u].y), e, acc[3]);
                } else {
                    acc[0] = fmaf(lo16(hv2[u]), e, acc[0]);
                    acc[1] = fmaf(hi16(hv2[u]), e, acc[1]);
                }
                ssum += e;
            }
        }

#pragma unroll
        for (int off = J; off < 64; off <<= 1) {
#pragma unroll
            for (int i = 0; i < NCH; i++) acc[i] += __shfl_xor(acc[i], off, 64);
            ssum += __shfl_xor(ssum, off, 64);
        }

        float inv = 1.0f / (ssum + 1e-16f);
        float v[NCH];
#pragma unroll
        for (int i = 0; i < NCH; i++) {
            float t = acc[i] * inv + bv[i];
            float en = __expf(fminf(t, 0.0f)) - 1.0f;  // ELU, native exp
            v[i] = t > 0.0f ? t : en;
        }

        if (FUSE) {
            float r = 0.0f;
#pragma unroll
            for (int i = 0; i < NCH; i++) r = fmaf(v[i], wov[i], r);
#pragma unroll
            for (int off = 1; off < J; off <<= 1) r += __shfl_xor(r, off, 64);
            if (lane == 0) {
                r += bov;
                if (bf) ((__hip_bfloat16*)xout)[node] = __float2bfloat16(r);
                else    ((float*)xout)[node] = r;
            }
        } else {
            if (p == 0) {
                if constexpr (NCH == 4) {
                    uint2 o; o.x = pack_bf16(v[0], v[1]); o.y = pack_bf16(v[2], v[3]);
                    ((uint2*)xout)[node * (HC / 4) + j] = o;
                } else {
                    ((unsigned*)xout)[node * (HC / 2) + j] = pack_bf16(v[0], v[1]);
                }
            }
        }
    }
}

// ---------------------------------------------------------------------------
extern "C" void kernel_launch(void* const* d_in, const int* in_sizes, int n_in,
                              void* d_out, int out_size, void* d_ws, size_t ws_size,
                              hipStream_t stream) {
    const void* x   = d_in[0];
    const int*  ei  = (const int*)d_in[1];
    const void* W1  = d_in[2];
    const void* as1 = d_in[3];
    const void* ad1 = d_in[4];
    const void* b1  = d_in[5];
    const void* W2  = d_in[6];
    const void* as2 = d_in[7];
    const void* ad2 = d_in[8];
    const void* b2  = d_in[9];
    const void* W3  = d_in[10];
    const void* as3 = d_in[11];
    const void* ad3 = d_in[12];
    const void* b3  = d_in[13];
    const void* Wo  = d_in[14];
    const void* bo  = d_in[15];

    const int N = in_sizes[0] / 3;
    const int E = in_sizes[1] / 2;
    const int* ei0 = ei;       // src
    const int* ei1 = ei + E;   // dst

    // ---- ws layout (~29.6 MB @ N=1e5, E=3.2e6; fits <32MB budget)
    int* flag   = (int*)d_ws;              // 64
    int* bcnt   = flag + 64;               // 1024
    int* bstart = bcnt + 1024;             // 1025 (padded 1088)
    int* bcur   = bstart + 1088;           // 1024
    int* cnt    = bcur + 1024;             // N
    int* rp     = cnt + N;                 // N
    int* ss     = rp + N;                  // E  (phase-A buf aliases this)
    float* als  = (float*)(ss + E);        // N*2 (node-major [N][2])
    float* ald  = als + (long)N * 2;       // N*2 (node-major [N][2])
    unsigned* A = (unsigned*)(ald + (long)N * 2); // N*16 u32
    unsigned* h = A + (long)N * 16;               // N*16 u32
    float4* xp  = (float4*)(h + (long)N * 16);    // N float4 (16B rows)
    float* cvec = (float*)(xp + (long)N);         // 12 floats

    const int B = 256;
    auto cdiv = [](long a, long b) { return (int)((a + b - 1) / b); };
    const int NBKT = cdiv(N, 256);   // 256-node buckets (R12)

    // persistent grids: 2048 blocks x 4 waves = 8 blocks/CU = 32 waves/CU.
    const int aggBlocks = 2048;

    // ---- two-level CSR build (dst-sorted), once, reused by all 3 layers
    prep<<<1, 1024, 0, stream>>>((const unsigned*)x, flag, bcnt);
    xprep<<<cdiv(N, B), B, 0, stream>>>(x, flag, W1, as1, ad1, xp, cvec, N);
    bhist<<<256, B, 0, stream>>>(ei1, E, bcnt);
    bscan<<<1, 1024, 0, stream>>>(bcnt, bstart, bcur);
    block_scatter<<<cdiv(E, CS_CHUNK), 512, 0, stream>>>(ei0, ei1, E, bcur, ss);
    fine_scatter<<<NBKT, B, 0, stream>>>(bstart, ss, ss, rp, cnt, N);

    // ---- Layer 1: 3 -> 2x16, commuted form: gather x (16B) only
    aggregate_l1<<<aggBlocks, B, 0, stream>>>(
        rp, cnt, ss, xp, cvec, W1, b1, flag, A, N);

    // ---- Layer 2: 32 -> 2x16 (combined-heads, node-major; R14 proven)
    node_transform<1, 32, 2, 16><<<cdiv(N, B), B, 0, stream>>>(
        A, flag, W2, as2, ad2, h, als, ald, N);
    aggregate<2, 16, 4, 6, 0><<<aggBlocks, B, 0, stream>>>(
        rp, cnt, ss, h, als, ald, b2, flag ? nullptr : nullptr, nullptr, flag, A, N);

    // ---- Layer 3: 32 -> 1x8, fused output head
    node_transform<1, 32, 1, 8><<<cdiv(N, B), B, 0, stream>>>(
        A, flag, W3, as3, ad3, h, als, ald, N);
    aggregate<1, 8, 2, 3, 1><<<aggBlocks, B, 0, stream>>>(
        rp, cnt, ss, h, als, ald, b3, Wo, bo, flag, d_out, N);
}

// Round 5
// 314.218 us; speedup vs baseline: 1.3231x; 1.0286x over previous
//
#include <hip/hip_runtime.h>
#include <hip/hip_bf16.h>
#include <math.h>

#define DEVINL __device__ __forceinline__

// Runtime-dtype load for EXTERNAL tensors: bf=1 -> bf16, bf=0 -> f32.
DEVINL float loadIn(const void* p, long i, int bf) {
    return bf ? __bfloat162float(((const __hip_bfloat16*)p)[i])
              : ((const float*)p)[i];
}

DEVINL float leaky(float v) { return fmaxf(v, 0.2f * v); }  // branch-free

DEVINL unsigned pack_bf16(float a, float b) {
    __hip_bfloat16 x = __float2bfloat16(a), y = __float2bfloat16(b);
    unsigned short ux = *reinterpret_cast<unsigned short*>(&x);
    unsigned short uy = *reinterpret_cast<unsigned short*>(&y);
    return (unsigned)ux | ((unsigned)uy << 16);
}
DEVINL float lo16(unsigned u) { return __uint_as_float(u << 16); }
DEVINL float hi16(unsigned u) { return __uint_as_float(u & 0xFFFF0000u); }

// ---------------------------------------------------------------------------
// prep: fused dtype sniffer (proven R2-R12) + bcnt zeroing. One block.
// ---------------------------------------------------------------------------
__global__ __launch_bounds__(1024) void prep(const unsigned* __restrict__ x,
                                             int* __restrict__ flag,
                                             int* __restrict__ bcnt) {
    __shared__ int sh[1024];
    int t = threadIdx.x;
    bcnt[t] = 0;
    int cnt = 0;
    for (int i = t; i < 2048; i += 1024) {
        unsigned ex = (x[i] >> 7) & 0xFFu;
        if (ex >= 110u && ex <= 140u) cnt++;
    }
    sh[t] = cnt;
    __syncthreads();
    for (int s = 512; s > 0; s >>= 1) {
        if (t < s) sh[t] += sh[t + s];
        __syncthreads();
    }
    if (t == 0) *flag = (sh[0] >= 1200) ? 1 : 0;
}

// ---------------------------------------------------------------------------
// Two-level CSR build. Bucket = dst >> 8 (256 nodes/bucket — R12 proven).
// ---------------------------------------------------------------------------
__global__ __launch_bounds__(256) void bhist(const int* __restrict__ dst, int E,
                                             int* __restrict__ bcnt) {
    __shared__ int lh[512];
    for (int i = threadIdx.x; i < 512; i += 256) lh[i] = 0;
    __syncthreads();
    int stride = gridDim.x * 256;
    for (int e = blockIdx.x * 256 + threadIdx.x; e < E; e += stride)
        atomicAdd(&lh[dst[e] >> 8], 1);
    __syncthreads();
    for (int i = threadIdx.x; i < 512; i += 256)
        if (lh[i]) atomicAdd(&bcnt[i], lh[i]);
}

__global__ __launch_bounds__(1024) void bscan(const int* __restrict__ bcnt,
                                              int* __restrict__ bstart,
                                              int* __restrict__ bcur) {
    __shared__ int sA[1024], sB[1024];
    int t = threadIdx.x;
    int c = bcnt[t];
    sA[t] = c;
    __syncthreads();
    int* a = sA; int* b = sB;
    for (int off = 1; off < 1024; off <<= 1) {
        int v = a[t] + ((t >= off) ? a[t - off] : 0);
        __syncthreads();
        b[t] = v;
        __syncthreads();
        int* tp = a; a = b; b = tp;
    }
    int excl = a[t] - c;
    bstart[t] = excl;
    bcur[t] = excl;
    if (t == 1023) bstart[1024] = a[t];
}

// Block-aggregated reservation scatter (R13 proven).
#define CS_CHUNK 16384
__global__ __launch_bounds__(512) void block_scatter(
    const int* __restrict__ srcIdx, const int* __restrict__ dstIdx, int E,
    int* __restrict__ bcur, int* __restrict__ buf) {
    __shared__ int lh[512];
    __shared__ int lcur[512];
    int t = threadIdx.x;
    int e0 = blockIdx.x * CS_CHUNK;
    int e1 = e0 + CS_CHUNK; if (e1 > E) e1 = E;

    if (t < 512) lh[t] = 0;
    __syncthreads();
    for (int e = e0 + t; e < e1; e += 512)
        atomicAdd(&lh[dstIdx[e] >> 8], 1);
    __syncthreads();
    if (t < 512) {
        int c = lh[t];
        lcur[t] = c ? atomicAdd(&bcur[t], c) : 0;
    }
    __syncthreads();
    for (int e = e0 + t; e < e1; e += 512) {
        int d = dstIdx[e];
        int s = srcIdx[e];
        int pos = atomicAdd(&lcur[d >> 8], 1);
        buf[pos] = ((d & 255) << 17) | s;   // src < 2^17 (N=1e5)
    }
}

// fine_scatter (R12 proven): one block per 256-node bucket.
#define FS_CAP 10240
__global__ __launch_bounds__(256) void fine_scatter(
    const int* __restrict__ bstart, int* buf, int* ss,
    int* __restrict__ rp, int* __restrict__ cnt, int N) {
    __shared__ int stage[FS_CAP];
    __shared__ int hcnt[256];
    __shared__ int hA[256], hB[256];
    __shared__ int lcur[256];
    int bkt = blockIdx.x;
    int t = threadIdx.x;
    int s0 = bstart[bkt];
    int m = bstart[bkt + 1] - s0;
    if (m > FS_CAP) m = FS_CAP;

    for (int i = t; i < m; i += 256) stage[i] = buf[s0 + i];
    hcnt[t] = 0;
    __syncthreads();
    for (int i = t; i < m; i += 256) atomicAdd(&hcnt[stage[i] >> 17], 1);
    __syncthreads();
    hA[t] = hcnt[t];
    __syncthreads();
    int* a = hA; int* b = hB;
    for (int off = 1; off < 256; off <<= 1) {
        int v = a[t] + ((t >= off) ? a[t - off] : 0);
        __syncthreads();
        b[t] = v;
        __syncthreads();
        int* tp = a; a = b; b = tp;
    }
    {
        int excl = a[t] - hcnt[t];
        lcur[t] = s0 + excl;
        int node = bkt * 256 + t;
        if (node < N) {
            rp[node] = s0 + excl;
            cnt[node] = hcnt[t];
        }
    }
    __syncthreads();
    for (int i = t; i < m; i += 256) {
        int v = stage[i];
        int pos = atomicAdd(&lcur[v >> 17], 1);
        ss[pos] = v & 0x1FFFF;
    }
}

// ---------------------------------------------------------------------------
// xprep (R17 proven): pad x -> xp[N][4] f32 + commuted attention vectors.
// ---------------------------------------------------------------------------
__global__ __launch_bounds__(256) void xprep(
    const void* __restrict__ x, const int* __restrict__ flagp,
    const void* __restrict__ W1, const void* __restrict__ as1,
    const void* __restrict__ ad1,
    float4* __restrict__ xp, float* __restrict__ cvec, int N)
{
    const int bf = *flagp;
    int n = blockIdx.x * 256 + threadIdx.x;
    if (n < N) {
        float4 v;
        v.x = loadIn(x, (long)n * 3 + 0, bf);
        v.y = loadIn(x, (long)n * 3 + 1, bf);
        v.z = loadIn(x, (long)n * 3 + 2, bf);
        v.w = 0.0f;
        xp[n] = v;
    }
    if (blockIdx.x == 0 && threadIdx.x < 12) {
        int t = threadIdx.x;
        int isd = t >= 6;
        int h = (t - 6 * isd) / 3;
        int k = (t - 6 * isd) % 3;
        const void* av = isd ? ad1 : as1;
        float s = 0.0f;
        for (int c = 0; c < 16; c++)
            s += loadIn(W1, k * 32 + h * 16 + c, bf) * loadIn(av, h * 16 + c, bf);
        cvec[t] = s;
    }
}

// ---------------------------------------------------------------------------
// aggregate_l1 (R17 proven): commuted layer-1 GAT, 16B/edge gather.
// ---------------------------------------------------------------------------
__global__ __launch_bounds__(256) void aggregate_l1(
    const int* __restrict__ rp_start, const int* __restrict__ cnt,
    const int* __restrict__ ss, const float4* __restrict__ xp,
    const float* __restrict__ cvec,
    const void* __restrict__ W1, const void* __restrict__ b1,
    const int* __restrict__ flagp,
    unsigned* __restrict__ xout, int N)
{
    const int bf = *flagp;
    __shared__ float Wl[96];
    __shared__ float bl[32];
    for (int i = threadIdx.x; i < 96; i += 256) Wl[i] = loadIn(W1, i, bf);
    for (int i = threadIdx.x; i < 32; i += 256) bl[i] = loadIn(b1, i, bf);
    __syncthreads();

    int lane = threadIdx.x & 63;
    int g = lane >> 4;
    int q = lane & 15;
    int wid = threadIdx.x >> 6;

    float cs[2][3], cd[2][3];
#pragma unroll
    for (int h = 0; h < 2; h++)
#pragma unroll
        for (int k = 0; k < 3; k++) {
            cs[h][k] = cvec[h * 3 + k];
            cd[h][k] = cvec[6 + h * 3 + k];
        }

    const int nstride = gridDim.x * 16;
    for (int node = blockIdx.x * 16 + wid * 4 + g; ; node += nstride) {
        if (node - g >= N) break;
        bool valid = node < N;
        int idx = valid ? node : 0;
        int start = rp_start[idx];
        int deg = valid ? cnt[idx] : 0;
        float4 xn = xp[idx];

        float alsn[2], aldn[2];
#pragma unroll
        for (int h = 0; h < 2; h++) {
            alsn[h] = xn.x * cs[h][0] + xn.y * cs[h][1] + xn.z * cs[h][2];
            aldn[h] = xn.x * cd[h][0] + xn.y * cd[h][1] + xn.z * cd[h][2];
        }

        float a00 = 0.f, a01 = 0.f, a02 = 0.f, s0 = 0.f;
        float a10 = 0.f, a11 = 0.f, a12 = 0.f, s1 = 0.f;

        if (q == 0 && valid) {
            float e0 = __expf(fminf(leaky(alsn[0] + aldn[0]), 80.0f));
            float e1 = __expf(fminf(leaky(alsn[1] + aldn[1]), 80.0f));
            a00 = e0 * xn.x; a01 = e0 * xn.y; a02 = e0 * xn.z; s0 = e0;
            a10 = e1 * xn.x; a11 = e1 * xn.y; a12 = e1 * xn.z; s1 = e1;
        }

        for (int kb = q; kb < deg; kb += 32) {
            int k2 = kb + 16;
            bool ok2 = k2 < deg;
            int sA = ss[start + kb];
            int sB = ss[start + (ok2 ? k2 : kb)];
            float4 xa = xp[sA];
            float4 xb = xp[sB];
            {
                float l0 = xa.x * cs[0][0] + xa.y * cs[0][1] + xa.z * cs[0][2] + aldn[0];
                float l1 = xa.x * cs[1][0] + xa.y * cs[1][1] + xa.z * cs[1][2] + aldn[1];
                float e0 = __expf(fminf(leaky(l0), 80.0f));
                float e1 = __expf(fminf(leaky(l1), 80.0f));
                a00 = fmaf(xa.x, e0, a00); a01 = fmaf(xa.y, e0, a01);
                a02 = fmaf(xa.z, e0, a02); s0 += e0;
                a10 = fmaf(xa.x, e1, a10); a11 = fmaf(xa.y, e1, a11);
                a12 = fmaf(xa.z, e1, a12); s1 += e1;
            }
            {
                float l0 = xb.x * cs[0][0] + xb.y * cs[0][1] + xb.z * cs[0][2] + aldn[0];
                float l1 = xb.x * cs[1][0] + xb.y * cs[1][1] + xb.z * cs[1][2] + aldn[1];
                float e0 = ok2 ? __expf(fminf(leaky(l0), 80.0f)) : 0.0f;
                float e1 = ok2 ? __expf(fminf(leaky(l1), 80.0f)) : 0.0f;
                a00 = fmaf(xb.x, e0, a00); a01 = fmaf(xb.y, e0, a01);
                a02 = fmaf(xb.z, e0, a02); s0 += e0;
                a10 = fmaf(xb.x, e1, a10); a11 = fmaf(xb.y, e1, a11);
                a12 = fmaf(xb.z, e1, a12); s1 += e1;
            }
        }

#pragma unroll
        for (int off = 1; off < 16; off <<= 1) {
            a00 += __shfl_xor(a00, off, 64); a01 += __shfl_xor(a01, off, 64);
            a02 += __shfl_xor(a02, off, 64); s0  += __shfl_xor(s0,  off, 64);
            a10 += __shfl_xor(a10, off, 64); a11 += __shfl_xor(a11, off, 64);
            a12 += __shfl_xor(a12, off, 64); s1  += __shfl_xor(s1,  off, 64);
        }

        if (valid) {
            int h = q >> 3;
            float inv = 1.0f / ((h ? s1 : s0) + 1e-16f);
            float g0 = (h ? a10 : a00) * inv;
            float g1 = (h ? a11 : a01) * inv;
            float g2 = (h ? a12 : a02) * inv;
            int c0 = 2 * q;
            float v0 = g0 * Wl[c0]      + g1 * Wl[32 + c0]      + g2 * Wl[64 + c0]      + bl[c0];
            float v1 = g0 * Wl[c0 + 1]  + g1 * Wl[32 + c0 + 1]  + g2 * Wl[64 + c0 + 1]  + bl[c0 + 1];
            v0 = v0 > 0.0f ? v0 : __expf(fminf(v0, 0.0f)) - 1.0f;
            v1 = v1 > 0.0f ? v1 : __expf(fminf(v1, 0.0f)) - 1.0f;
            xout[(long)node * 16 + q] = pack_bf16(v0, v1);
        }
    }
}

// ---------------------------------------------------------------------------
// node_transform (R9/R1 proven, node-major). Layers 2-3 only.
// ---------------------------------------------------------------------------
template <int XMODE, int C_IN, int H, int C>
__global__ __launch_bounds__(256) void node_transform(
    const void* __restrict__ xin, const int* __restrict__ flagp,
    const void* __restrict__ W, const void* __restrict__ a_s,
    const void* __restrict__ a_d,
    unsigned* __restrict__ h2, float* __restrict__ als,
    float* __restrict__ ald, int N)
{
    const int bf = *flagp;
    constexpr int HC = H * C;
    __shared__ float Ws[C_IN * HC];
    __shared__ float asS[HC];
    __shared__ float adS[HC];
    for (int i = threadIdx.x; i < C_IN * HC; i += 256) Ws[i] = loadIn(W, i, bf);
    for (int i = threadIdx.x; i < HC; i += 256) {
        asS[i] = loadIn(a_s, i, bf);
        adS[i] = loadIn(a_d, i, bf);
    }
    __syncthreads();

    int n = blockIdx.x * 256 + threadIdx.x;
    if (n >= N) return;

    float xv[C_IN];
    if (XMODE) {
        const uint4* x4 = (const uint4*)xin;
#pragma unroll
        for (int q = 0; q < C_IN / 8; q++) {
            uint4 w = x4[(long)n * (C_IN / 8) + q];
            xv[q * 8 + 0] = lo16(w.x); xv[q * 8 + 1] = hi16(w.x);
            xv[q * 8 + 2] = lo16(w.y); xv[q * 8 + 3] = hi16(w.y);
            xv[q * 8 + 4] = lo16(w.z); xv[q * 8 + 5] = hi16(w.z);
            xv[q * 8 + 6] = lo16(w.w); xv[q * 8 + 7] = hi16(w.w);
        }
    } else {
#pragma unroll
        for (int k = 0; k < C_IN; k++) xv[k] = loadIn(xin, (long)n * C_IN + k, bf);
    }

    float hv[HC];
#pragma unroll
    for (int j = 0; j < HC; j++) {
        float v = 0.0f;
#pragma unroll
        for (int k = 0; k < C_IN; k++) v = fmaf(xv[k], Ws[k * HC + j], v);
        hv[j] = v;
    }
#pragma unroll
    for (int jj = 0; jj < HC / 2; jj++)
        h2[(long)n * (HC / 2) + jj] = pack_bf16(hv[2 * jj], hv[2 * jj + 1]);

#pragma unroll
    for (int hh = 0; hh < H; hh++) {
        float vs = 0.0f, vd = 0.0f;
#pragma unroll
        for (int c = 0; c < C; c++) {
            vs = fmaf(hv[hh * C + c], asS[hh * C + c], vs);
            vd = fmaf(hv[hh * C + c], adS[hh * C + c], vd);
        }
        als[(long)n * H + hh] = vs;
        ald[(long)n * H + hh] = vd;
    }
}

// ---------------------------------------------------------------------------
// aggregate (R18): combined-heads node-major structure (R14, 69us), now with
// a 2-deep CROSS-NODE software pipeline. Evidence: R1 (-25% issue -> -3%
// time) rules out issue-bound; R3 (FETCH/2 -> time worse) rules out BW-bound;
// => gather-latency-bound. Steady-state body for node n:
//   (a) issue als/h2 gathers for n+ns   (ss landed during previous body)
//   (b) prefetch CSR+selfloop for n+2ns
//   (c) compute n                       (gathers had a full body to land)
//   (e) issue ss for n+2ns              (CSR landed during compute)
//   (d) finish n (butterfly/epilogue/store)
// All pipeline state in explicitly-suffixed registers (rule #20: no
// runtime-indexed arrays -> no scratch). deg>SLOTS tail (0.3% of nodes,
// wave-uniform branch) runs a serial remainder loop.
// ---------------------------------------------------------------------------
template <int H, int C, int NCH, int UNR, int FUSE>
__global__ __launch_bounds__(256) void aggregate(
    const int* __restrict__ rp_start, const int* __restrict__ cnt,
    const int* __restrict__ ss,
    const unsigned* __restrict__ h2,
    const float* __restrict__ als, const float* __restrict__ ald,
    const void* __restrict__ bias, const void* __restrict__ Wo,
    const void* __restrict__ bo, const int* __restrict__ flagp,
    void* __restrict__ xout, int N)
{
    constexpr int HC = H * C;
    constexpr int J = HC / NCH;     // lanes per edge row
    constexpr int EPW = 64 / J;     // edge rows per wave
    constexpr int SLOTS = UNR * EPW;
    const int bf = *flagp;
    int lane = threadIdx.x & 63;
    int p = lane / J;
    int j = lane % J;
    int c0 = NCH * j;
    int head = c0 / C;
    const float* __restrict__ alsH = als + head;

    float bv[NCH];
#pragma unroll
    for (int i = 0; i < NCH; i++) bv[i] = loadIn(bias, c0 + i, bf);
    float wov[NCH];
    float bov = 0.0f;
    if constexpr (FUSE) {
#pragma unroll
        for (int i = 0; i < NCH; i++) wov[i] = loadIn(Wo, c0 + i, bf);
        bov = loadIn(bo, 0, bf);
    }

    const int nstride = gridDim.x << 2;   // 4 waves per block
    const int node0 = (blockIdx.x << 2) + (threadIdx.x >> 6);
    if (node0 >= N) return;

    // ---- pipeline state: 2 slots, all statically indexed
    int nd0, nd1, st0, st1, dg0, dg1;
    float an0, an1, sa0, sa1;
    uint2 sq0, sq1; unsigned sw0, sw1;           // self h row fragments
    int sr0[UNR], sr1[UNR];
    float av0[UNR], av1[UNR];
    uint2 hq0[UNR], hq1[UNR];
    unsigned hw0[UNR], hw1[UNR];

#define AGG_LOADCSR(S, NODE) {                                              \
    int nn_ = (NODE); nd##S = nn_;                                          \
    int ii_ = nn_ < N ? nn_ : N - 1;                                        \
    st##S = rp_start[ii_];                                                  \
    dg##S = nn_ < N ? cnt[ii_] : 0;                                         \
    an##S = ald[ii_ * H + head];                                            \
    sa##S = alsH[ii_ * H];                                                  \
    if constexpr (NCH == 4) sq##S = ((const uint2*)h2)[ii_ * (HC / 4) + j]; \
    else sw##S = h2[ii_ * (HC / 2) + j]; }

#define AGG_ISSUE_SS(S) {                                                   \
    int dm1_ = dg##S > 0 ? dg##S - 1 : 0;                                   \
    _Pragma("unroll") for (int u = 0; u < UNR; u++) {                       \
        int k_ = p + u * EPW;                                               \
        sr##S[u] = ss[st##S + (k_ < dg##S ? k_ : dm1_)]; } }

#define AGG_ISSUE_G(S) {                                                    \
    _Pragma("unroll") for (int u = 0; u < UNR; u++) {                       \
        av##S[u] = alsH[sr##S[u] * H];                                      \
        if constexpr (NCH == 4)                                             \
            hq##S[u] = ((const uint2*)h2)[sr##S[u] * (HC / 4) + j];         \
        else hw##S[u] = h2[sr##S[u] * (HC / 2) + j]; } }

#define AGG_BODY(A, B) {                                                    \
    int node_c = nd##A, start_c = st##A, deg_c = dg##A;                     \
    float an_c = an##A, sa_c = sa##A;                                       \
    uint2 sq_c = sq##A; unsigned sw_c = sw##A; (void)sq_c; (void)sw_c;      \
    /* (a) issue gathers for NXT */                                         \
    AGG_ISSUE_G(B);                                                         \
    /* (b) prefetch CSR+self for node_c + 2*nstride into slot A */          \
    AGG_LOADCSR(A, node_c + 2 * nstride);                                   \
    /* (c) compute CUR */                                                   \
    float acc[NCH]; float ssum = 0.0f;                                      \
    _Pragma("unroll") for (int i = 0; i < NCH; i++) acc[i] = 0.0f;          \
    if (p == 0) {                                                           \
        float es_ = __expf(fminf(leaky(sa_c + an_c), 80.0f));               \
        if constexpr (NCH == 4) {                                           \
            acc[0] = lo16(sq_c.x) * es_; acc[1] = hi16(sq_c.x) * es_;       \
            acc[2] = lo16(sq_c.y) * es_; acc[3] = hi16(sq_c.y) * es_;       \
        } else {                                                            \
            acc[0] = lo16(sw_c) * es_; acc[1] = hi16(sw_c) * es_;           \
        }                                                                   \
        ssum = es_;                                                         \
    }                                                                       \
    _Pragma("unroll") for (int u = 0; u < UNR; u++) {                       \
        int k_ = p + u * EPW;                                               \
        float e_ = (k_ < deg_c)                                             \
            ? __expf(fminf(leaky(av##A[u] + an_c), 80.0f)) : 0.0f;          \
        if constexpr (NCH == 4) {                                           \
            acc[0] = fmaf(lo16(hq##A[u].x), e_, acc[0]);                    \
            acc[1] = fmaf(hi16(hq##A[u].x), e_, acc[1]);                    \
            acc[2] = fmaf(lo16(hq##A[u].y), e_, acc[2]);                    \
            acc[3] = fmaf(hi16(hq##A[u].y), e_, acc[3]);                    \
        } else {                                                            \
            acc[0] = fmaf(lo16(hw##A[u]), e_, acc[0]);                      \
            acc[1] = fmaf(hi16(hw##A[u]), e_, acc[1]);                      \
        }                                                                   \
        ssum += e_;                                                         \
    }                                                                       \
    /* rare tail: deg > SLOTS (wave-uniform branch) */                      \
    if (deg_c > SLOTS) {                                                    \
        for (int kb_ = SLOTS + p; kb_ < deg_c; kb_ += EPW) {                \
            int s_ = ss[start_c + kb_];                                     \
            float e_ = __expf(fminf(leaky(alsH[s_ * H] + an_c), 80.0f));    \
            if constexpr (NCH == 4) {                                       \
                uint2 hv_ = ((const uint2*)h2)[s_ * (HC / 4) + j];          \
                acc[0] = fmaf(lo16(hv_.x), e_, acc[0]);                     \
                acc[1] = fmaf(hi16(hv_.x), e_, acc[1]);                     \
                acc[2] = fmaf(lo16(hv_.y), e_, acc[2]);                     \
                acc[3] = fmaf(hi16(hv_.y), e_, acc[3]);                     \
            } else {                                                        \
                unsigned hv_ = h2[s_ * (HC / 2) + j];                       \
                acc[0] = fmaf(lo16(hv_), e_, acc[0]);                       \
                acc[1] = fmaf(hi16(hv_), e_, acc[1]);                       \
            }                                                               \
            ssum += e_;                                                     \
        }                                                                   \
    }                                                                       \
    /* (e) issue ss for N2 (CSR slot A landed during compute) */            \
    AGG_ISSUE_SS(A);                                                        \
    /* (d) finish CUR */                                                    \
    _Pragma("unroll") for (int off = J; off < 64; off <<= 1) {              \
        _Pragma("unroll") for (int i = 0; i < NCH; i++)                     \
            acc[i] += __shfl_xor(acc[i], off, 64);                          \
        ssum += __shfl_xor(ssum, off, 64);                                  \
    }                                                                       \
    float inv = 1.0f / (ssum + 1e-16f);                                     \
    float v[NCH];                                                           \
    _Pragma("unroll") for (int i = 0; i < NCH; i++) {                       \
        float t_ = acc[i] * inv + bv[i];                                    \
        v[i] = t_ > 0.0f ? t_ : __expf(fminf(t_, 0.0f)) - 1.0f;             \
    }                                                                       \
    if constexpr (FUSE) {                                                   \
        float r_ = 0.0f;                                                    \
        _Pragma("unroll") for (int i = 0; i < NCH; i++)                     \
            r_ = fmaf(v[i], wov[i], r_);                                    \
        _Pragma("unroll") for (int off = 1; off < J; off <<= 1)             \
            r_ += __shfl_xor(r_, off, 64);                                  \
        if (lane == 0 && node_c < N) {                                      \
            r_ += bov;                                                      \
            if (bf) ((__hip_bfloat16*)xout)[node_c] = __float2bfloat16(r_); \
            else    ((float*)xout)[node_c] = r_;                            \
        }                                                                   \
    } else {                                                                \
        if (p == 0 && node_c < N) {                                         \
            if constexpr (NCH == 4) {                                       \
                uint2 o_; o_.x = pack_bf16(v[0], v[1]);                     \
                o_.y = pack_bf16(v[2], v[3]);                               \
                ((uint2*)xout)[node_c * (HC / 4) + j] = o_;                 \
            } else {                                                        \
                ((unsigned*)xout)[node_c * (HC / 2) + j] =                  \
                    pack_bf16(v[0], v[1]);                                  \
            }                                                               \
        }                                                                   \
    } }

    // ---- prologue: fill slots 0 (node0) and 1 (node0+ns)
    AGG_LOADCSR(0, node0);
    AGG_LOADCSR(1, node0 + nstride);
    AGG_ISSUE_SS(0);
    AGG_ISSUE_G(0);
    AGG_ISSUE_SS(1);

    for (;;) {
        AGG_BODY(0, 1);
        if (nd1 >= N) break;
        AGG_BODY(1, 0);
        if (nd0 >= N) break;
    }

#undef AGG_LOADCSR
#undef AGG_ISSUE_SS
#undef AGG_ISSUE_G
#undef AGG_BODY
}

// ---------------------------------------------------------------------------
extern "C" void kernel_launch(void* const* d_in, const int* in_sizes, int n_in,
                              void* d_out, int out_size, void* d_ws, size_t ws_size,
                              hipStream_t stream) {
    const void* x   = d_in[0];
    const int*  ei  = (const int*)d_in[1];
    const void* W1  = d_in[2];
    const void* as1 = d_in[3];
    const void* ad1 = d_in[4];
    const void* b1  = d_in[5];
    const void* W2  = d_in[6];
    const void* as2 = d_in[7];
    const void* ad2 = d_in[8];
    const void* b2  = d_in[9];
    const void* W3  = d_in[10];
    const void* as3 = d_in[11];
    const void* ad3 = d_in[12];
    const void* b3  = d_in[13];
    const void* Wo  = d_in[14];
    const void* bo  = d_in[15];

    const int N = in_sizes[0] / 3;
    const int E = in_sizes[1] / 2;
    const int* ei0 = ei;       // src
    const int* ei1 = ei + E;   // dst

    // ---- ws layout (~29.6 MB @ N=1e5, E=3.2e6; fits <32MB budget)
    int* flag   = (int*)d_ws;              // 64
    int* bcnt   = flag + 64;               // 1024
    int* bstart = bcnt + 1024;             // 1025 (padded 1088)
    int* bcur   = bstart + 1088;           // 1024
    int* cnt    = bcur + 1024;             // N
    int* rp     = cnt + N;                 // N
    int* ss     = rp + N;                  // E  (phase-A buf aliases this)
    float* als  = (float*)(ss + E);        // N*2 (node-major [N][2])
    float* ald  = als + (long)N * 2;       // N*2 (node-major [N][2])
    unsigned* A = (unsigned*)(ald + (long)N * 2); // N*16 u32
    unsigned* h = A + (long)N * 16;               // N*16 u32
    float4* xp  = (float4*)(h + (long)N * 16);    // N float4 (16B rows)
    float* cvec = (float*)(xp + (long)N);         // 12 floats

    const int B = 256;
    auto cdiv = [](long a, long b) { return (int)((a + b - 1) / b); };
    const int NBKT = cdiv(N, 256);   // 256-node buckets (R12)

    // persistent grids: 2048 blocks x 4 waves (grid-stride over nodes)
    const int aggBlocks = 2048;

    // ---- two-level CSR build (dst-sorted), once, reused by all 3 layers
    prep<<<1, 1024, 0, stream>>>((const unsigned*)x, flag, bcnt);
    xprep<<<cdiv(N, B), B, 0, stream>>>(x, flag, W1, as1, ad1, xp, cvec, N);
    bhist<<<256, B, 0, stream>>>(ei1, E, bcnt);
    bscan<<<1, 1024, 0, stream>>>(bcnt, bstart, bcur);
    block_scatter<<<cdiv(E, CS_CHUNK), 512, 0, stream>>>(ei0, ei1, E, bcur, ss);
    fine_scatter<<<NBKT, B, 0, stream>>>(bstart, ss, ss, rp, cnt, N);

    // ---- Layer 1: 3 -> 2x16, commuted form: gather x (16B) only
    aggregate_l1<<<aggBlocks, B, 0, stream>>>(
        rp, cnt, ss, xp, cvec, W1, b1, flag, A, N);

    // ---- Layer 2: 32 -> 2x16 (combined-heads, pipelined aggregate)
    node_transform<1, 32, 2, 16><<<cdiv(N, B), B, 0, stream>>>(
        A, flag, W2, as2, ad2, h, als, ald, N);
    aggregate<2, 16, 4, 6, 0><<<aggBlocks, B, 0, stream>>>(
        rp, cnt, ss, h, als, ald, b2, nullptr, nullptr, flag, A, N);

    // ---- Layer 3: 32 -> 1x8, fused output head (pipelined aggregate)
    node_transform<1, 32, 1, 8><<<cdiv(N, B), B, 0, stream>>>(
        A, flag, W3, as3, ad3, h, als, ald, N);
    aggregate<1, 8, 2, 3, 1><<<aggBlocks, B, 0, stream>>>(
        rp, cnt, ss, h, als, ald, b3, Wo, bo, flag, d_out, N);
}